// Round 4
// baseline (2420.321 us; speedup 1.0000x reference)
//
#include <hip/hip_runtime.h>
#include <hip/hip_fp16.h>

#define DD 1024
#define LL 128
#define NSEG 64

typedef _Float16 half8  __attribute__((ext_vector_type(8)));
typedef float    floatx4 __attribute__((ext_vector_type(4)));
typedef float    f4v     __attribute__((ext_vector_type(4)));

// ---- prep: build swizzled f16 Wab2 so B-frag loads are 1KB-contiguous ----
// Wab2 element gid: j=gid&7, lhi=(gid>>3)&3, llo=(gid>>5)&15, ks=(gid>>9)&31, ct=gid>>14
// holds W[ct*16+llo][ks*32+lhi*8+j]  (rows 0..127 = Wa, 128..255 = Wb)
__global__ __launch_bounds__(256)
void prep_kernel(const float* __restrict__ Wa, const float* __restrict__ Wb,
                 _Float16* __restrict__ Wab2, unsigned* __restrict__ smaxu,
                 float* __restrict__ denom)
{
    int gid = blockIdx.x * 256 + threadIdx.x;
    if (gid < 2 * LL * DD) {
        const int j   = gid & 7;
        const int lhi = (gid >> 3) & 3;
        const int llo = (gid >> 5) & 15;
        const int ks  = (gid >> 9) & 31;
        const int ct  = gid >> 14;
        const int r = ct * 16 + llo;
        const int k = ks * 32 + lhi * 8 + j;
        const float v = (r < LL) ? Wa[r * DD + k] : Wb[(r - LL) * DD + k];
        Wab2[gid] = (_Float16)v;
    }
    if (gid < NSEG)          smaxu[gid] = 0u;
    else if (gid < 2 * NSEG) denom[gid - NSEG] = 0.0f;
}

#define WAITVM(n) asm volatile("s_waitcnt vmcnt(" #n ")" ::: "memory")
#define SB() __builtin_amdgcn_sched_barrier(0)

// ---- fused, wave-standalone: 16 rows/wave, LDS DMA ring, counted vmcnt ----
__global__ __launch_bounds__(256, 2)
void fused_main(const float* __restrict__ feat,
                const _Float16* __restrict__ Wab2,
                const float* __restrict__ ba,
                const float* __restrict__ bb,
                const float* __restrict__ Wc,
                const float* __restrict__ bc,
                float* __restrict__ out_norm,
                float* __restrict__ score_raw)
{
    __shared__ __align__(16) float lds[4 * 4096];   // 64 KB: per-wave 16 KB = 4 slots x 4 KB

    const int tid  = threadIdx.x;
    const int wave = tid >> 6;
    const int lane = tid & 63;
    const int s15  = lane & 15;      // A-frag row selector
    const int l4   = lane >> 4;      // A-frag k-slice selector
    const long long row0 = ((long long)blockIdx.x * 4 + wave) * 16;

    float* wlds = &lds[wave * 4096];

    // chunk c covers feat cols [c*64, c*64+64) of the 16 rows.
    // LDS unit (16B) U = i*64+L maps to (row rU=U>>4, slot sU=U&15); slot sU holds
    // global unit g = sU ^ (rU&7)  (XOR swizzle applied on the SOURCE side).
    auto issue = [&](int c) {
        float* lb = wlds + (c & 3) * 1024;
        #pragma unroll
        for (int i = 0; i < 4; ++i) {
            const int row = i * 4 + l4;
            const int xr  = ((i & 1) << 2) | l4;            // row&7
            const float* g = feat + (size_t)(row0 + row) * DD + c * 64 + ((s15 ^ xr) << 2);
            __builtin_amdgcn_global_load_lds(
                (const __attribute__((address_space(1))) void*)g,
                (__attribute__((address_space(3))) void*)(lb + i * 256),
                16, 0, 0);
        }
    };

    half8 af[32];
    float ssA = 0.0f, ssB = 0.0f;
    const int u0 = ((l4 * 2) ^ (s15 & 7));

    auto process = [&](int c) {
        const float* rb = wlds + (c & 3) * 1024 + s15 * 64;
        f4v q0 = *(const f4v*)(rb + (u0 << 2));             // global floats [lhi*8,   +4)
        f4v q1 = *(const f4v*)(rb + ((u0 ^ 1) << 2));       // [lhi*8+4, +4)
        f4v q2 = *(const f4v*)(rb + ((u0 + 8) << 2));       // [32+lhi*8, +4)
        f4v q3 = *(const f4v*)(rb + (((u0 ^ 1) + 8) << 2)); // [32+lhi*8+4, +4)
        ssA += q0[0]*q0[0] + q0[1]*q0[1] + q0[2]*q0[2] + q0[3]*q0[3]
             + q1[0]*q1[0] + q1[1]*q1[1] + q1[2]*q1[2] + q1[3]*q1[3];
        ssB += q2[0]*q2[0] + q2[1]*q2[1] + q2[2]*q2[2] + q2[3]*q2[3]
             + q3[0]*q3[0] + q3[1]*q3[1] + q3[2]*q3[2] + q3[3]*q3[3];
        half8 h0, h1;
        h0[0]=(_Float16)q0[0]; h0[1]=(_Float16)q0[1]; h0[2]=(_Float16)q0[2]; h0[3]=(_Float16)q0[3];
        h0[4]=(_Float16)q1[0]; h0[5]=(_Float16)q1[1]; h0[6]=(_Float16)q1[2]; h0[7]=(_Float16)q1[3];
        h1[0]=(_Float16)q2[0]; h1[1]=(_Float16)q2[1]; h1[2]=(_Float16)q2[2]; h1[3]=(_Float16)q2[3];
        h1[4]=(_Float16)q3[0]; h1[5]=(_Float16)q3[1]; h1[6]=(_Float16)q3[2]; h1[7]=(_Float16)q3[3];
        af[2 * c]     = h0;
        af[2 * c + 1] = h1;
    };

    // ---------------- phase 1: DMA ring, 3 chunks (12 KB) in flight ----------------
    issue(0); issue(1); issue(2);
    issue(3);  WAITVM(12); SB(); process(0);
    issue(4);  WAITVM(12); SB(); process(1);
    issue(5);  WAITVM(12); SB(); process(2);
    issue(6);  WAITVM(12); SB(); process(3);
    issue(7);  WAITVM(12); SB(); process(4);
    issue(8);  WAITVM(12); SB(); process(5);
    issue(9);  WAITVM(12); SB(); process(6);
    issue(10); WAITVM(12); SB(); process(7);
    issue(11); WAITVM(12); SB(); process(8);
    issue(12); WAITVM(12); SB(); process(9);
    issue(13); WAITVM(12); SB(); process(10);
    issue(14); WAITVM(12); SB(); process(11);
    issue(15); WAITVM(12); SB(); process(12);
    WAITVM(8);  SB(); process(13);
    WAITVM(4);  SB(); process(14);
    WAITVM(0);  SB(); process(15);

    float ss = ssA + ssB;
    ss += __shfl_xor(ss, 16); ss += __shfl_xor(ss, 32);     // reduce over l4
    const float rinv = 1.0f / fmaxf(sqrtf(ss), 1e-12f);

    // ---------------- phase 2: out_norm stores + dual GEMM from registers ----------------
    floatx4 acc[16];
    #pragma unroll
    for (int ct = 0; ct < 16; ++ct) acc[ct] = (floatx4)0.0f;

    float* ob = out_norm + (size_t)(row0 + s15) * DD + l4 * 8;
    const int wlane = (s15 * 4 + l4) * 8;

    #pragma unroll
    for (int ks = 0; ks < 32; ++ks) {
        const half8 a = af[ks];
        f4v o0, o1;
        o0[0] = (float)a[0] * rinv; o0[1] = (float)a[1] * rinv;
        o0[2] = (float)a[2] * rinv; o0[3] = (float)a[3] * rinv;
        o1[0] = (float)a[4] * rinv; o1[1] = (float)a[5] * rinv;
        o1[2] = (float)a[6] * rinv; o1[3] = (float)a[7] * rinv;
        *reinterpret_cast<f4v*>(ob + ks * 32)     = o0;
        *reinterpret_cast<f4v*>(ob + ks * 32 + 4) = o1;
        #pragma unroll
        for (int ct = 0; ct < 16; ++ct) {
            const half8 b = *reinterpret_cast<const half8*>(Wab2 + ((ct * 32 + ks) << 9) + wlane);
            acc[ct] = __builtin_amdgcn_mfma_f32_16x16x32_f16(a, b, acc[ct], 0, 0, 0);
        }
    }

    // ---------------- epilogue: sigmoid(a)*tanh(b) . Wc ----------------
    float s[4] = {0.f, 0.f, 0.f, 0.f};
    #pragma unroll
    for (int ct = 0; ct < 8; ++ct) {
        const int c = ct * 16 + s15;
        const float bav = ba[c], bbv = bb[c], wcv = Wc[c];
        #pragma unroll
        for (int j = 0; j < 4; ++j) {
            const float av = 1.0f / (1.0f + expf(-(acc[ct][j] + bav)));
            const float bv = tanhf(acc[ct + 8][j] + bbv);
            s[j] += av * bv * wcv;
        }
    }
    #pragma unroll
    for (int j = 0; j < 4; ++j) {
        s[j] += __shfl_xor(s[j], 1);
        s[j] += __shfl_xor(s[j], 2);
        s[j] += __shfl_xor(s[j], 4);
        s[j] += __shfl_xor(s[j], 8);
    }
    if (s15 == 0) {
        const float bcv = bc[0];
        #pragma unroll
        for (int j = 0; j < 4; ++j)
            score_raw[row0 + l4 * 4 + j] = s[j] + bcv;
    }
}

// ---------------- segment softmax (3 tiny passes over N floats) ----------------
__global__ __launch_bounds__(256)
void seg_max_kernel(const float* __restrict__ score, const int* __restrict__ batch,
                    unsigned* __restrict__ smaxu, int n)
{
    __shared__ unsigned sm[NSEG];
    const int t = threadIdx.x;
    if (t < NSEG) sm[t] = 0u;
    __syncthreads();
    const int stride = gridDim.x * blockDim.x;
    for (int i = blockIdx.x * blockDim.x + t; i < n; i += stride) {
        const unsigned b = __float_as_uint(score[i]);
        const unsigned m = (b & 0x80000000u) ? ~b : (b | 0x80000000u);
        atomicMax(&sm[batch[i]], m);
    }
    __syncthreads();
    if (t < NSEG) atomicMax(&smaxu[t], sm[t]);
}

__global__ __launch_bounds__(256)
void seg_exp_kernel(float* __restrict__ score_inout, const int* __restrict__ batch,
                    const unsigned* __restrict__ smaxu, float* __restrict__ denom, int n)
{
    __shared__ float sd[NSEG];
    __shared__ float smx[NSEG];
    const int t = threadIdx.x;
    if (t < NSEG) {
        sd[t] = 0.0f;
        const unsigned u = smaxu[t];
        const unsigned b = (u & 0x80000000u) ? (u ^ 0x80000000u) : ~u;
        smx[t] = __uint_as_float(b);
    }
    __syncthreads();
    const int stride = gridDim.x * blockDim.x;
    for (int i = blockIdx.x * blockDim.x + t; i < n; i += stride) {
        const int b = batch[i];
        const float e = expf(score_inout[i] - smx[b]);
        score_inout[i] = e;
        atomicAdd(&sd[b], e);
    }
    __syncthreads();
    if (t < NSEG) atomicAdd(&denom[t], sd[t]);
}

__global__ __launch_bounds__(256)
void seg_div_kernel(float* __restrict__ score_inout, const int* __restrict__ batch,
                    const float* __restrict__ denom, int n)
{
    const int stride = gridDim.x * blockDim.x;
    for (int i = blockIdx.x * blockDim.x + threadIdx.x; i < n; i += stride)
        score_inout[i] = score_inout[i] / (denom[batch[i]] + 1e-16f);
}

// ---------------------------------------------------------------------------
extern "C" void kernel_launch(void* const* d_in, const int* in_sizes, int n_in,
                              void* d_out, int out_size, void* d_ws, size_t ws_size,
                              hipStream_t stream)
{
    const float* feat  = (const float*)d_in[0];
    const int*   batch = (const int*)d_in[1];
    // d_in[2] = istrain (unused; dropout is identity at eval)
    const float* Wa = (const float*)d_in[3];
    const float* ba = (const float*)d_in[4];
    const float* Wb = (const float*)d_in[5];
    const float* bb = (const float*)d_in[6];
    const float* Wc = (const float*)d_in[7];
    const float* bc = (const float*)d_in[8];

    const int N = in_sizes[1];                 // 262144

    float* out_norm  = (float*)d_out;
    float* out_score = (float*)d_out + (size_t)N * DD;

    char* ws = (char*)d_ws;
    _Float16* Wab2  = (_Float16*)ws;                         // 512 KB
    unsigned* smaxu = (unsigned*)(ws + 2 * LL * DD * 2);     // 64 u32
    float*    denom = (float*)(ws + 2 * LL * DD * 2 + 256);  // 64 f32

    prep_kernel<<<(2 * LL * DD + 255) / 256, 256, 0, stream>>>(Wa, Wb, Wab2, smaxu, denom);
    // 4 waves/block x 16 rows/wave = 64 rows/block
    fused_main<<<N / 64, 256, 0, stream>>>(feat, Wab2, ba, bb, Wc, bc, out_norm, out_score);
    seg_max_kernel<<<512, 256, 0, stream>>>(out_score, batch, smaxu, N);
    seg_exp_kernel<<<512, 256, 0, stream>>>(out_score, batch, smaxu, denom, N);
    seg_div_kernel<<<512, 256, 0, stream>>>(out_score, batch, denom, N);
}

// Round 5
// 766.315 us; speedup vs baseline: 3.1584x; 3.1584x over previous
//
#include <hip/hip_runtime.h>
#include <hip/hip_fp16.h>

#define DD 1024
#define LL 128
#define NSEG 64

typedef _Float16 half8  __attribute__((ext_vector_type(8)));
typedef _Float16 half4v __attribute__((ext_vector_type(4)));
typedef float    floatx4 __attribute__((ext_vector_type(4)));

// ---- prep: build swizzled f16 Wab2 so B-frag loads are 1KB-contiguous ----
// Wab2 element gid = (ct*32 + ks)*512 + (s15*4 + l4)*8 + j
// holds W[ct*16+s15][ks*32 + l4*8 + j]   (rows 0..127 = Wa, 128..255 = Wb)
__global__ __launch_bounds__(256)
void prep_kernel(const float* __restrict__ Wa, const float* __restrict__ Wb,
                 _Float16* __restrict__ Wab2, unsigned* __restrict__ smaxu,
                 float* __restrict__ denom)
{
    int gid = blockIdx.x * 256 + threadIdx.x;
    if (gid < 2 * LL * DD) {
        const int j   = gid & 7;
        const int l4  = (gid >> 3) & 3;
        const int s15 = (gid >> 5) & 15;
        const int ks  = (gid >> 9) & 31;
        const int ct  = gid >> 14;
        const int r = ct * 16 + s15;
        const int k = ks * 32 + l4 * 8 + j;
        const float v = (r < LL) ? Wa[r * DD + k] : Wb[(r - LL) * DD + k];
        Wab2[gid] = (_Float16)v;
    }
    if (gid < NSEG)          smaxu[gid] = 0u;
    else if (gid < 2 * NSEG) denom[gid - NSEG] = 0.0f;
}

// ---- fused: 16-row tile per 256-thr block, 4 blocks/CU, 2 barriers ----
__global__ __launch_bounds__(256, 4)
void fused_main(const float* __restrict__ feat,
                const _Float16* __restrict__ Wab2,
                const float* __restrict__ ba,
                const float* __restrict__ bb,
                const float* __restrict__ Wc,
                const float* __restrict__ bc,
                float* __restrict__ out_norm,
                float* __restrict__ score_raw)
{
    // af-order f16 tile: unit(ks,r,l4) = ks*64 + r*4 + l4 (16B units) -> 32 KB
    __shared__ __align__(16) _Float16 tile[32 * 64 * 8];
    __shared__ float scorebuf[16];

    const int tid  = threadIdx.x;
    const int wave = tid >> 6;
    const int lane = tid & 63;
    const int s15  = lane & 15;
    const int l4   = lane >> 4;
    const long long row0 = (long long)blockIdx.x * 16;

    if (tid < 16) scorebuf[tid] = 0.0f;

    // ---------------- Phase A: 4 rows/wave, full-row addressing ----------------
    // All 16 loads issued upfront (independent, 1KB contiguous per instruction).
    float4 L[4][4];
    {
        const float* fb = feat + (size_t)(row0 + wave * 4) * DD + lane * 4;
        #pragma unroll
        for (int i = 0; i < 4; ++i)
            #pragma unroll
            for (int c = 0; c < 4; ++c)
                L[i][c] = *reinterpret_cast<const float4*>(fb + (size_t)i * DD + c * 256);
    }

    #pragma unroll
    for (int i = 0; i < 4; ++i) {
        const int r = wave * 4 + i;
        float ss = 0.0f;
        #pragma unroll
        for (int c = 0; c < 4; ++c)
            ss += L[i][c].x * L[i][c].x + L[i][c].y * L[i][c].y
                + L[i][c].z * L[i][c].z + L[i][c].w * L[i][c].w;
        #pragma unroll
        for (int off = 32; off >= 1; off >>= 1) ss += __shfl_xor(ss, off);
        const float rinv = 1.0f / fmaxf(sqrtf(ss), 1e-12f);

        float* ob = out_norm + (size_t)(row0 + r) * DD + lane * 4;
        #pragma unroll
        for (int c = 0; c < 4; ++c) {
            float4 v;
            v.x = L[i][c].x * rinv; v.y = L[i][c].y * rinv;
            v.z = L[i][c].z * rinv; v.w = L[i][c].w * rinv;
            *reinterpret_cast<float4*>(ob + c * 256) = v;
        }
        // f16 convert + LDS write in MFMA-fragment order
        #pragma unroll
        for (int c = 0; c < 4; ++c) {
            half4v h;
            h[0] = (_Float16)L[i][c].x; h[1] = (_Float16)L[i][c].y;
            h[2] = (_Float16)L[i][c].z; h[3] = (_Float16)L[i][c].w;
            const int ks   = c * 8 + (lane >> 3);
            const int unit = ks * 64 + r * 4 + ((lane >> 1) & 3);
            *reinterpret_cast<half4v*>(
                reinterpret_cast<char*>(tile) + unit * 16 + (lane & 1) * 8) = h;
        }
    }
    __syncthreads();

    // ---------------- Phase B: MFMA dual GEMM, wave owns 64 a-cols + 64 b-cols ----
    floatx4 acc[4];
    #pragma unroll
    for (int n = 0; n < 4; ++n) acc[n] = (floatx4)0.0f;

    const int t0 = 2 * wave;          // a-tiles t0, t0+1 ; b-tiles t0+8, t0+9
    const _Float16* wb = Wab2 + (size_t)(s15 * 4 + l4) * 8;

    #pragma unroll 8
    for (int ks = 0; ks < 32; ++ks) {
        const half8 a = *reinterpret_cast<const half8*>(tile + (ks * 64 + s15 * 4 + l4) * 8);
        const half8 b0 = *reinterpret_cast<const half8*>(wb + (((t0 + 0) * 32 + ks) << 9));
        const half8 b1 = *reinterpret_cast<const half8*>(wb + (((t0 + 1) * 32 + ks) << 9));
        const half8 b2 = *reinterpret_cast<const half8*>(wb + (((t0 + 8) * 32 + ks) << 9));
        const half8 b3 = *reinterpret_cast<const half8*>(wb + (((t0 + 9) * 32 + ks) << 9));
        acc[0] = __builtin_amdgcn_mfma_f32_16x16x32_f16(a, b0, acc[0], 0, 0, 0);
        acc[1] = __builtin_amdgcn_mfma_f32_16x16x32_f16(a, b1, acc[1], 0, 0, 0);
        acc[2] = __builtin_amdgcn_mfma_f32_16x16x32_f16(a, b2, acc[2], 0, 0, 0);
        acc[3] = __builtin_amdgcn_mfma_f32_16x16x32_f16(a, b3, acc[3], 0, 0, 0);
    }

    // ---------------- epilogue: sigmoid(a)*tanh(b) . Wc ----------------
    float s[4] = {0.f, 0.f, 0.f, 0.f};
    #pragma unroll
    for (int n = 0; n < 2; ++n) {
        const int col = (t0 + n) * 16 + s15;
        const float bav = ba[col], bbv = bb[col], wcv = Wc[col];
        #pragma unroll
        for (int j = 0; j < 4; ++j) {
            const float av = 1.0f / (1.0f + expf(-(acc[n][j] + bav)));
            const float bv = tanhf(acc[n + 2][j] + bbv);
            s[j] += av * bv * wcv;
        }
    }
    #pragma unroll
    for (int j = 0; j < 4; ++j) {
        s[j] += __shfl_xor(s[j], 1);
        s[j] += __shfl_xor(s[j], 2);
        s[j] += __shfl_xor(s[j], 4);
        s[j] += __shfl_xor(s[j], 8);
    }
    if (s15 == 0) {
        #pragma unroll
        for (int j = 0; j < 4; ++j)
            atomicAdd(&scorebuf[l4 * 4 + j], s[j]);
    }
    __syncthreads();
    if (tid < 16) score_raw[row0 + tid] = scorebuf[tid] + bc[0];
}

// ---------------- segment softmax (3 tiny passes over N floats) ----------------
__global__ __launch_bounds__(256)
void seg_max_kernel(const float* __restrict__ score, const int* __restrict__ batch,
                    unsigned* __restrict__ smaxu, int n)
{
    __shared__ unsigned sm[NSEG];
    const int t = threadIdx.x;
    if (t < NSEG) sm[t] = 0u;
    __syncthreads();
    const int stride = gridDim.x * blockDim.x;
    for (int i = blockIdx.x * blockDim.x + t; i < n; i += stride) {
        const unsigned b = __float_as_uint(score[i]);
        const unsigned m = (b & 0x80000000u) ? ~b : (b | 0x80000000u);
        atomicMax(&sm[batch[i]], m);
    }
    __syncthreads();
    if (t < NSEG) atomicMax(&smaxu[t], sm[t]);
}

__global__ __launch_bounds__(256)
void seg_exp_kernel(float* __restrict__ score_inout, const int* __restrict__ batch,
                    const unsigned* __restrict__ smaxu, float* __restrict__ denom, int n)
{
    __shared__ float sd[NSEG];
    __shared__ float smx[NSEG];
    const int t = threadIdx.x;
    if (t < NSEG) {
        sd[t] = 0.0f;
        const unsigned u = smaxu[t];
        const unsigned b = (u & 0x80000000u) ? (u ^ 0x80000000u) : ~u;
        smx[t] = __uint_as_float(b);
    }
    __syncthreads();
    const int stride = gridDim.x * blockDim.x;
    for (int i = blockIdx.x * blockDim.x + t; i < n; i += stride) {
        const int b = batch[i];
        const float e = expf(score_inout[i] - smx[b]);
        score_inout[i] = e;
        atomicAdd(&sd[b], e);
    }
    __syncthreads();
    if (t < NSEG) atomicAdd(&denom[t], sd[t]);
}

__global__ __launch_bounds__(256)
void seg_div_kernel(float* __restrict__ score_inout, const int* __restrict__ batch,
                    const float* __restrict__ denom, int n)
{
    const int stride = gridDim.x * blockDim.x;
    for (int i = blockIdx.x * blockDim.x + threadIdx.x; i < n; i += stride)
        score_inout[i] = score_inout[i] / (denom[batch[i]] + 1e-16f);
}

// ---------------------------------------------------------------------------
extern "C" void kernel_launch(void* const* d_in, const int* in_sizes, int n_in,
                              void* d_out, int out_size, void* d_ws, size_t ws_size,
                              hipStream_t stream)
{
    const float* feat  = (const float*)d_in[0];
    const int*   batch = (const int*)d_in[1];
    // d_in[2] = istrain (unused; dropout is identity at eval)
    const float* Wa = (const float*)d_in[3];
    const float* ba = (const float*)d_in[4];
    const float* Wb = (const float*)d_in[5];
    const float* bb = (const float*)d_in[6];
    const float* Wc = (const float*)d_in[7];
    const float* bc = (const float*)d_in[8];

    const int N = in_sizes[1];                 // 262144

    float* out_norm  = (float*)d_out;
    float* out_score = (float*)d_out + (size_t)N * DD;

    char* ws = (char*)d_ws;
    _Float16* Wab2  = (_Float16*)ws;                         // 512 KB
    unsigned* smaxu = (unsigned*)(ws + 2 * LL * DD * 2);     // 64 u32
    float*    denom = (float*)(ws + 2 * LL * DD * 2 + 256);  // 64 f32

    prep_kernel<<<(2 * LL * DD + 255) / 256, 256, 0, stream>>>(Wa, Wb, Wab2, smaxu, denom);
    fused_main<<<N / 16, 256, 0, stream>>>(feat, Wab2, ba, bb, Wc, bc, out_norm, out_score);
    seg_max_kernel<<<512, 256, 0, stream>>>(out_score, batch, smaxu, N);
    seg_exp_kernel<<<512, 256, 0, stream>>>(out_score, batch, smaxu, denom, N);
    seg_div_kernel<<<512, 256, 0, stream>>>(out_score, batch, denom, N);
}

// Round 6
// 741.232 us; speedup vs baseline: 3.2653x; 1.0338x over previous
//
#include <hip/hip_runtime.h>
#include <hip/hip_fp16.h>

#define DD 1024
#define LL 128
#define NSEG 64

typedef _Float16 half8  __attribute__((ext_vector_type(8)));
typedef float    floatx4 __attribute__((ext_vector_type(4)));

// ---- prep: build chunk-major f16 Wab3 + zero seg buffers ----
// Wab3 gid = c*16384 + (ct*2+ks)*512 + lane*8 + j   (c = K-chunk of 64)
// holds W[ct*16 + (lane&15)][c*64 + ks*32 + (lane>>4)*8 + j]
// rows 0..127 = Wa, 128..255 = Wb.  This is the exact ds_read fragment order.
__global__ __launch_bounds__(256)
void prep_kernel(const float* __restrict__ Wa, const float* __restrict__ Wb,
                 _Float16* __restrict__ Wab3, unsigned* __restrict__ smaxu,
                 float* __restrict__ denom)
{
    int gid = blockIdx.x * 256 + threadIdx.x;
    if (gid < 2 * LL * DD) {
        const int j    = gid & 7;
        const int lane = (gid >> 3) & 63;
        const int s15  = lane & 15;
        const int l4   = lane >> 4;
        const int ks   = (gid >> 9) & 1;
        const int ct   = (gid >> 10) & 15;
        const int c    = gid >> 14;
        const int r = ct * 16 + s15;
        const int k = c * 64 + ks * 32 + l4 * 8 + j;
        const float v = (r < LL) ? Wa[r * DD + k] : Wb[(r - LL) * DD + k];
        Wab3[gid] = (_Float16)v;
    }
    if (gid < NSEG)          smaxu[gid] = 0u;
    else if (gid < 2 * NSEG) denom[gid - NSEG] = 0.0f;
}

// ---- K2: MFMA GEMM, 512 thr, 128 rows/block, B via LDS 2-phase pipeline ----
__global__ __launch_bounds__(512, 4)
void gemm_kernel(const float* __restrict__ feat,
                 const _Float16* __restrict__ Wab3,
                 const float* __restrict__ ba,
                 const float* __restrict__ bb,
                 const float* __restrict__ Wc,
                 const float* __restrict__ bc,
                 float* __restrict__ score_raw)
{
    __shared__ __align__(16) _Float16 Bb[2][16384];   // 2 x 32 KB K-chunk buffers

    const int tid  = threadIdx.x;
    const int wave = tid >> 6;
    const int lane = tid & 63;
    const int s15  = lane & 15;
    const int l4   = lane >> 4;
    const long long row0 = (long long)blockIdx.x * 128;

    const float* arow = feat + (size_t)(row0 + wave * 16 + s15) * DD + l4 * 8;

    // stage K-chunk c of Wab3 (32 KB) into Bb[c&1] via direct-to-LDS DMA
    auto stage = [&](int c) {
        const _Float16* src = Wab3 + (size_t)c * 16384 + tid * 8;
        _Float16* dst = Bb[c & 1] + tid * 8;
        #pragma unroll
        for (int r = 0; r < 4; ++r)
            __builtin_amdgcn_global_load_lds(
                (const __attribute__((address_space(1))) void*)(src + r * 4096),
                (__attribute__((address_space(3))) void*)(dst + r * 4096),
                16, 0, 0);
    };

    floatx4 acc[16];
    #pragma unroll
    for (int ct = 0; ct < 16; ++ct) acc[ct] = (floatx4)0.0f;

    stage(0);
    __syncthreads();

    for (int c = 0; c < 16; ++c) {
        if (c + 1 < 16) stage(c + 1);            // prefetch next chunk (other buffer)

        const float4* ap = reinterpret_cast<const float4*>(arow + c * 64);
        const float4 a00 = ap[0], a01 = ap[1];   // ks=0: k in [c*64+l4*8, +8)
        const float4 a10 = ap[8], a11 = ap[9];   // ks=1: +32
        half8 af0, af1;
        af0[0]=(_Float16)a00.x; af0[1]=(_Float16)a00.y; af0[2]=(_Float16)a00.z; af0[3]=(_Float16)a00.w;
        af0[4]=(_Float16)a01.x; af0[5]=(_Float16)a01.y; af0[6]=(_Float16)a01.z; af0[7]=(_Float16)a01.w;
        af1[0]=(_Float16)a10.x; af1[1]=(_Float16)a10.y; af1[2]=(_Float16)a10.z; af1[3]=(_Float16)a10.w;
        af1[4]=(_Float16)a11.x; af1[5]=(_Float16)a11.y; af1[6]=(_Float16)a11.z; af1[7]=(_Float16)a11.w;

        const _Float16* bbase = Bb[c & 1] + lane * 8;
        #pragma unroll
        for (int ct = 0; ct < 16; ++ct) {
            const half8 b0 = *reinterpret_cast<const half8*>(bbase + (ct * 2 + 0) * 512);
            const half8 b1 = *reinterpret_cast<const half8*>(bbase + (ct * 2 + 1) * 512);
            acc[ct] = __builtin_amdgcn_mfma_f32_16x16x32_f16(af0, b0, acc[ct], 0, 0, 0);
            acc[ct] = __builtin_amdgcn_mfma_f32_16x16x32_f16(af1, b1, acc[ct], 0, 0, 0);
        }
        __syncthreads();   // everyone done with Bb[c&1]; drains stage(c+1) DMA
    }

    // ---- epilogue: sigmoid(a)*tanh(b) . Wc -> per-row raw score ----
    float s[4] = {0.f, 0.f, 0.f, 0.f};
    #pragma unroll
    for (int ct = 0; ct < 8; ++ct) {
        const int col = ct * 16 + s15;
        const float bav = ba[col], bbv = bb[col], wcv = Wc[col];
        #pragma unroll
        for (int j = 0; j < 4; ++j) {
            const float av = 1.0f / (1.0f + expf(-(acc[ct][j] + bav)));
            const float bv = tanhf(acc[ct + 8][j] + bbv);
            s[j] += av * bv * wcv;
        }
    }
    #pragma unroll
    for (int j = 0; j < 4; ++j) {
        s[j] += __shfl_xor(s[j], 1);
        s[j] += __shfl_xor(s[j], 2);
        s[j] += __shfl_xor(s[j], 4);
        s[j] += __shfl_xor(s[j], 8);
    }
    if (s15 == 0) {
        const float bcv = bc[0];
        #pragma unroll
        for (int j = 0; j < 4; ++j)
            score_raw[row0 + wave * 16 + l4 * 4 + j] = s[j] + bcv;
    }
}

// ---- K1: pure-streaming row L2-normalize (32 waves/CU, copy-like) ----
__global__ __launch_bounds__(256, 8)
void norm_kernel(const float* __restrict__ feat, float* __restrict__ out_norm, int n)
{
    const int lane = threadIdx.x & 63;
    const int gw   = (blockIdx.x * 256 + threadIdx.x) >> 6;   // 0..8191

    #pragma unroll 2
    for (int row = gw; row < n; row += 8192) {
        const float4* src = reinterpret_cast<const float4*>(feat + (size_t)row * DD) + lane;
        const float4 v0 = src[0], v1 = src[64], v2 = src[128], v3 = src[192];
        float ss = v0.x*v0.x + v0.y*v0.y + v0.z*v0.z + v0.w*v0.w
                 + v1.x*v1.x + v1.y*v1.y + v1.z*v1.z + v1.w*v1.w
                 + v2.x*v2.x + v2.y*v2.y + v2.z*v2.z + v2.w*v2.w
                 + v3.x*v3.x + v3.y*v3.y + v3.z*v3.z + v3.w*v3.w;
        #pragma unroll
        for (int off = 32; off >= 1; off >>= 1) ss += __shfl_xor(ss, off);
        const float rinv = 1.0f / fmaxf(sqrtf(ss), 1e-12f);

        float4* dst = reinterpret_cast<float4*>(out_norm + (size_t)row * DD) + lane;
        float4 o;
        o.x=v0.x*rinv; o.y=v0.y*rinv; o.z=v0.z*rinv; o.w=v0.w*rinv; dst[0]   = o;
        o.x=v1.x*rinv; o.y=v1.y*rinv; o.z=v1.z*rinv; o.w=v1.w*rinv; dst[64]  = o;
        o.x=v2.x*rinv; o.y=v2.y*rinv; o.z=v2.z*rinv; o.w=v2.w*rinv; dst[128] = o;
        o.x=v3.x*rinv; o.y=v3.y*rinv; o.z=v3.z*rinv; o.w=v3.w*rinv; dst[192] = o;
    }
}

// ---------------- segment softmax (3 tiny passes over N floats) ----------------
__global__ __launch_bounds__(256)
void seg_max_kernel(const float* __restrict__ score, const int* __restrict__ batch,
                    unsigned* __restrict__ smaxu, int n)
{
    __shared__ unsigned sm[NSEG];
    const int t = threadIdx.x;
    if (t < NSEG) sm[t] = 0u;
    __syncthreads();
    const int stride = gridDim.x * blockDim.x;
    for (int i = blockIdx.x * blockDim.x + t; i < n; i += stride) {
        const unsigned b = __float_as_uint(score[i]);
        const unsigned m = (b & 0x80000000u) ? ~b : (b | 0x80000000u);
        atomicMax(&sm[batch[i]], m);
    }
    __syncthreads();
    if (t < NSEG) atomicMax(&smaxu[t], sm[t]);
}

__global__ __launch_bounds__(256)
void seg_exp_kernel(float* __restrict__ score_inout, const int* __restrict__ batch,
                    const unsigned* __restrict__ smaxu, float* __restrict__ denom, int n)
{
    __shared__ float sd[NSEG];
    __shared__ float smx[NSEG];
    const int t = threadIdx.x;
    if (t < NSEG) {
        sd[t] = 0.0f;
        const unsigned u = smaxu[t];
        const unsigned b = (u & 0x80000000u) ? (u ^ 0x80000000u) : ~u;
        smx[t] = __uint_as_float(b);
    }
    __syncthreads();
    const int stride = gridDim.x * blockDim.x;
    for (int i = blockIdx.x * blockDim.x + t; i < n; i += stride) {
        const int b = batch[i];
        const float e = expf(score_inout[i] - smx[b]);
        score_inout[i] = e;
        atomicAdd(&sd[b], e);
    }
    __syncthreads();
    if (t < NSEG) atomicAdd(&denom[t], sd[t]);
}

__global__ __launch_bounds__(256)
void seg_div_kernel(float* __restrict__ score_inout, const int* __restrict__ batch,
                    const float* __restrict__ denom, int n)
{
    const int stride = gridDim.x * blockDim.x;
    for (int i = blockIdx.x * blockDim.x + threadIdx.x; i < n; i += stride)
        score_inout[i] = score_inout[i] / (denom[batch[i]] + 1e-16f);
}

// ---------------------------------------------------------------------------
extern "C" void kernel_launch(void* const* d_in, const int* in_sizes, int n_in,
                              void* d_out, int out_size, void* d_ws, size_t ws_size,
                              hipStream_t stream)
{
    const float* feat  = (const float*)d_in[0];
    const int*   batch = (const int*)d_in[1];
    // d_in[2] = istrain (unused; dropout is identity at eval)
    const float* Wa = (const float*)d_in[3];
    const float* ba = (const float*)d_in[4];
    const float* Wb = (const float*)d_in[5];
    const float* bb = (const float*)d_in[6];
    const float* Wc = (const float*)d_in[7];
    const float* bc = (const float*)d_in[8];

    const int N = in_sizes[1];                 // 262144

    float* out_norm  = (float*)d_out;
    float* out_score = (float*)d_out + (size_t)N * DD;

    char* ws = (char*)d_ws;
    _Float16* Wab3  = (_Float16*)ws;                         // 512 KB
    unsigned* smaxu = (unsigned*)(ws + 2 * LL * DD * 2);     // 64 u32
    float*    denom = (float*)(ws + 2 * LL * DD * 2 + 256);  // 64 f32

    prep_kernel<<<(2 * LL * DD + 255) / 256, 256, 0, stream>>>(Wa, Wb, Wab3, smaxu, denom);
    gemm_kernel<<<N / 128, 512, 0, stream>>>(feat, Wab3, ba, bb, Wc, bc, out_score);
    norm_kernel<<<2048, 256, 0, stream>>>(feat, out_norm, N);
    seg_max_kernel<<<512, 256, 0, stream>>>(out_score, batch, smaxu, N);
    seg_exp_kernel<<<512, 256, 0, stream>>>(out_score, batch, smaxu, denom, N);
    seg_div_kernel<<<512, 256, 0, stream>>>(out_score, batch, denom, N);
}

// Round 7
// 685.400 us; speedup vs baseline: 3.5313x; 1.0815x over previous
//
#include <hip/hip_runtime.h>
#include <hip/hip_fp16.h>

#define DD 1024
#define LL 128
#define NSEG 64

typedef _Float16 half8  __attribute__((ext_vector_type(8)));
typedef float    floatx4 __attribute__((ext_vector_type(4)));

// ---- prep: build chunk-major f16 Wab3 + zero seg buffers ----
// Wab3 gid = c*16384 + (ct*2+ks)*512 + lane*8 + j   (c = K-chunk of 64)
// holds W[ct*16 + (lane&15)][c*64 + ks*32 + (lane>>4)*8 + j]
// rows 0..127 = Wa, 128..255 = Wb.  Exact ds_read fragment order.
__global__ __launch_bounds__(256)
void prep_kernel(const float* __restrict__ Wa, const float* __restrict__ Wb,
                 _Float16* __restrict__ Wab3, unsigned* __restrict__ smaxu,
                 float* __restrict__ denom)
{
    int gid = blockIdx.x * 256 + threadIdx.x;
    if (gid < 2 * LL * DD) {
        const int j    = gid & 7;
        const int lane = (gid >> 3) & 63;
        const int s15  = lane & 15;
        const int l4   = lane >> 4;
        const int ks   = (gid >> 9) & 1;
        const int ct   = (gid >> 10) & 15;
        const int c    = gid >> 14;
        const int r = ct * 16 + s15;
        const int k = c * 64 + ks * 32 + l4 * 8 + j;
        const float v = (r < LL) ? Wa[r * DD + k] : Wb[(r - LL) * DD + k];
        Wab3[gid] = (_Float16)v;
    }
    if (gid < NSEG)          smaxu[gid] = 0u;
    else if (gid < 2 * NSEG) denom[gid - NSEG] = 0.0f;
}

// ---- heterogeneous kernel: even role = MFMA GEMM block, odd role = norm streamer ----
// role bit taken from (bid>>3)&1 so both roles spread across all 8 XCDs.
__global__ __launch_bounds__(512, 4)
void fused_all(const float* __restrict__ feat,
               const _Float16* __restrict__ Wab3,
               const float* __restrict__ ba,
               const float* __restrict__ bb,
               const float* __restrict__ Wc,
               const float* __restrict__ bc,
               float* __restrict__ out_norm,
               float* __restrict__ score_raw,
               int n)
{
    __shared__ __align__(16) _Float16 Bb[2][16384];   // 2 x 32 KB K-chunk buffers

    const int bid  = blockIdx.x;
    const int tid  = threadIdx.x;
    const int lane = tid & 63;
    const int role = (bid >> 3) & 1;
    const int rid  = ((bid >> 4) << 3) | (bid & 7);   // 0..2047 within role

    if (role == 1) {
        // ---------------- norm role: pure streaming row L2-normalize ----------------
        const int wv = rid * 8 + (tid >> 6);          // 0..16383
        #pragma unroll 2
        for (int row = wv; row < n; row += 16384) {
            const float4* src = reinterpret_cast<const float4*>(feat + (size_t)row * DD) + lane;
            const float4 v0 = src[0], v1 = src[64], v2 = src[128], v3 = src[192];
            float ss = v0.x*v0.x + v0.y*v0.y + v0.z*v0.z + v0.w*v0.w
                     + v1.x*v1.x + v1.y*v1.y + v1.z*v1.z + v1.w*v1.w
                     + v2.x*v2.x + v2.y*v2.y + v2.z*v2.z + v2.w*v2.w
                     + v3.x*v3.x + v3.y*v3.y + v3.z*v3.z + v3.w*v3.w;
            #pragma unroll
            for (int off = 32; off >= 1; off >>= 1) ss += __shfl_xor(ss, off);
            const float rinv = 1.0f / fmaxf(sqrtf(ss), 1e-12f);

            float4* dst = reinterpret_cast<float4*>(out_norm + (size_t)row * DD) + lane;
            float4 o;
            o.x=v0.x*rinv; o.y=v0.y*rinv; o.z=v0.z*rinv; o.w=v0.w*rinv; dst[0]   = o;
            o.x=v1.x*rinv; o.y=v1.y*rinv; o.z=v1.z*rinv; o.w=v1.w*rinv; dst[64]  = o;
            o.x=v2.x*rinv; o.y=v2.y*rinv; o.z=v2.z*rinv; o.w=v2.w*rinv; dst[128] = o;
            o.x=v3.x*rinv; o.y=v3.y*rinv; o.z=v3.z*rinv; o.w=v3.w*rinv; dst[192] = o;
        }
        return;
    }

    // ---------------- gemm role: 128 rows/block, B via LDS 2-phase pipeline ----------------
    const int wave = tid >> 6;
    const int s15  = lane & 15;
    const int l4   = lane >> 4;
    const long long row0 = (long long)rid * 128;

    const float* arow = feat + (size_t)(row0 + wave * 16 + s15) * DD + l4 * 8;

    auto stage = [&](int c) {
        const _Float16* src = Wab3 + (size_t)c * 16384 + tid * 8;
        _Float16* dst = Bb[c & 1] + tid * 8;
        #pragma unroll
        for (int r = 0; r < 4; ++r)
            __builtin_amdgcn_global_load_lds(
                (const __attribute__((address_space(1))) void*)(src + r * 4096),
                (__attribute__((address_space(3))) void*)(dst + r * 4096),
                16, 0, 0);
    };

    floatx4 acc[16];
    #pragma unroll
    for (int ct = 0; ct < 16; ++ct) acc[ct] = (floatx4)0.0f;

    // prologue: stage B(0), load A(0)
    stage(0);
    float4 a0, a1, a2, a3;
    {
        const float4* ap = reinterpret_cast<const float4*>(arow);
        a0 = ap[0]; a1 = ap[1]; a2 = ap[8]; a3 = ap[9];
    }
    __syncthreads();

    for (int c = 0; c < 16; ++c) {
        float4 n0, n1, n2, n3;
        if (c + 1 < 16) {
            stage(c + 1);                           // B prefetch (other buffer)
            const float4* ap = reinterpret_cast<const float4*>(arow + (c + 1) * 64);
            n0 = ap[0]; n1 = ap[1]; n2 = ap[8]; n3 = ap[9];   // A prefetch
        }

        half8 af0, af1;
        af0[0]=(_Float16)a0.x; af0[1]=(_Float16)a0.y; af0[2]=(_Float16)a0.z; af0[3]=(_Float16)a0.w;
        af0[4]=(_Float16)a1.x; af0[5]=(_Float16)a1.y; af0[6]=(_Float16)a1.z; af0[7]=(_Float16)a1.w;
        af1[0]=(_Float16)a2.x; af1[1]=(_Float16)a2.y; af1[2]=(_Float16)a2.z; af1[3]=(_Float16)a2.w;
        af1[4]=(_Float16)a3.x; af1[5]=(_Float16)a3.y; af1[6]=(_Float16)a3.z; af1[7]=(_Float16)a3.w;

        const _Float16* bbase = Bb[c & 1] + lane * 8;
        #pragma unroll
        for (int ct = 0; ct < 16; ++ct) {
            const half8 b0 = *reinterpret_cast<const half8*>(bbase + (ct * 2 + 0) * 512);
            const half8 b1 = *reinterpret_cast<const half8*>(bbase + (ct * 2 + 1) * 512);
            acc[ct] = __builtin_amdgcn_mfma_f32_16x16x32_f16(af0, b0, acc[ct], 0, 0, 0);
            acc[ct] = __builtin_amdgcn_mfma_f32_16x16x32_f16(af1, b1, acc[ct], 0, 0, 0);
        }
        __syncthreads();   // everyone done with Bb[c&1]; drains stage(c+1) + A prefetch
        a0 = n0; a1 = n1; a2 = n2; a3 = n3;
    }

    // ---- epilogue: sigmoid(a)*tanh(b) . Wc -> per-row raw score ----
    float s[4] = {0.f, 0.f, 0.f, 0.f};
    #pragma unroll
    for (int ct = 0; ct < 8; ++ct) {
        const int col = ct * 16 + s15;
        const float bav = ba[col], bbv = bb[col], wcv = Wc[col];
        #pragma unroll
        for (int j = 0; j < 4; ++j) {
            const float av = 1.0f / (1.0f + expf(-(acc[ct][j] + bav)));
            const float bv = tanhf(acc[ct + 8][j] + bbv);
            s[j] += av * bv * wcv;
        }
    }
    #pragma unroll
    for (int j = 0; j < 4; ++j) {
        s[j] += __shfl_xor(s[j], 1);
        s[j] += __shfl_xor(s[j], 2);
        s[j] += __shfl_xor(s[j], 4);
        s[j] += __shfl_xor(s[j], 8);
    }
    if (s15 == 0) {
        const float bcv = bc[0];
        #pragma unroll
        for (int j = 0; j < 4; ++j)
            score_raw[row0 + wave * 16 + l4 * 4 + j] = s[j] + bcv;
    }
}

// ---------------- segment softmax (3 tiny passes over N floats) ----------------
__global__ __launch_bounds__(256)
void seg_max_kernel(const float* __restrict__ score, const int* __restrict__ batch,
                    unsigned* __restrict__ smaxu, int n)
{
    __shared__ unsigned sm[NSEG];
    const int t = threadIdx.x;
    if (t < NSEG) sm[t] = 0u;
    __syncthreads();
    const int stride = gridDim.x * blockDim.x;
    for (int i = blockIdx.x * blockDim.x + t; i < n; i += stride) {
        const unsigned b = __float_as_uint(score[i]);
        const unsigned m = (b & 0x80000000u) ? ~b : (b | 0x80000000u);
        atomicMax(&sm[batch[i]], m);
    }
    __syncthreads();
    if (t < NSEG) atomicMax(&smaxu[t], sm[t]);
}

__global__ __launch_bounds__(256)
void seg_exp_kernel(float* __restrict__ score_inout, const int* __restrict__ batch,
                    const unsigned* __restrict__ smaxu, float* __restrict__ denom, int n)
{
    __shared__ float sd[NSEG];
    __shared__ float smx[NSEG];
    const int t = threadIdx.x;
    if (t < NSEG) {
        sd[t] = 0.0f;
        const unsigned u = smaxu[t];
        const unsigned b = (u & 0x80000000u) ? (u ^ 0x80000000u) : ~u;
        smx[t] = __uint_as_float(b);
    }
    __syncthreads();
    const int stride = gridDim.x * blockDim.x;
    for (int i = blockIdx.x * blockDim.x + t; i < n; i += stride) {
        const int b = batch[i];
        const float e = expf(score_inout[i] - smx[b]);
        score_inout[i] = e;
        atomicAdd(&sd[b], e);
    }
    __syncthreads();
    if (t < NSEG) atomicAdd(&denom[t], sd[t]);
}

__global__ __launch_bounds__(256)
void seg_div_kernel(float* __restrict__ score_inout, const int* __restrict__ batch,
                    const float* __restrict__ denom, int n)
{
    const int stride = gridDim.x * blockDim.x;
    for (int i = blockIdx.x * blockDim.x + threadIdx.x; i < n; i += stride)
        score_inout[i] = score_inout[i] / (denom[batch[i]] + 1e-16f);
}

// ---------------------------------------------------------------------------
extern "C" void kernel_launch(void* const* d_in, const int* in_sizes, int n_in,
                              void* d_out, int out_size, void* d_ws, size_t ws_size,
                              hipStream_t stream)
{
    const float* feat  = (const float*)d_in[0];
    const int*   batch = (const int*)d_in[1];
    // d_in[2] = istrain (unused; dropout is identity at eval)
    const float* Wa = (const float*)d_in[3];
    const float* ba = (const float*)d_in[4];
    const float* Wb = (const float*)d_in[5];
    const float* bb = (const float*)d_in[6];
    const float* Wc = (const float*)d_in[7];
    const float* bc = (const float*)d_in[8];

    const int N = in_sizes[1];                 // 262144

    float* out_norm  = (float*)d_out;
    float* out_score = (float*)d_out + (size_t)N * DD;

    char* ws = (char*)d_ws;
    _Float16* Wab3  = (_Float16*)ws;                         // 512 KB
    unsigned* smaxu = (unsigned*)(ws + 2 * LL * DD * 2);     // 64 u32
    float*    denom = (float*)(ws + 2 * LL * DD * 2 + 256);  // 64 f32

    prep_kernel<<<(2 * LL * DD + 255) / 256, 256, 0, stream>>>(Wa, Wb, Wab3, smaxu, denom);
    // 4096 blocks: role bit (bid>>3)&1 -> 2048 gemm-role + 2048 norm-role, XCD-mixed
    fused_all<<<4096, 512, 0, stream>>>(feat, Wab3, ba, bb, Wc, bc, out_norm, out_score, N);
    seg_max_kernel<<<512, 256, 0, stream>>>(out_score, batch, smaxu, N);
    seg_exp_kernel<<<512, 256, 0, stream>>>(out_score, batch, smaxu, denom, N);
    seg_div_kernel<<<512, 256, 0, stream>>>(out_score, batch, denom, N);
}